// Round 1
// baseline (7823.792 us; speedup 1.0000x reference)
//
#include <hip/hip_runtime.h>
#include <hip/hip_bf16.h>

// Problem dims
// N=128, T=128, D=1024, H=1024, 4H=4096, K = H(h) + H(attn) + D(x) = 3072

typedef __bf16 bf16x8 __attribute__((ext_vector_type(8)));
typedef float f32x4 __attribute__((ext_vector_type(4)));

__device__ __forceinline__ unsigned short f2bf(float f) {
    unsigned int u = __float_as_uint(f);
    u += 0x7FFFu + ((u >> 16) & 1u);   // round-to-nearest-even
    return (unsigned short)(u >> 16);
}
__device__ __forceinline__ float sigf(float x) { return 1.0f / (1.0f + expf(-x)); }

// ---------------------------------------------------------------------------
// Build WT[4096][3072] bf16: WT[c][k] = Wcomb[k][orig_col], where reordered
// col c = 4*unit + gate  <->  orig_col = gate*1024 + unit, and K rows are
// [0,1024): Wh, [1024,2048): Wattn, [2048,3072): Wx  (matching act layout).
// ---------------------------------------------------------------------------
__global__ __launch_bounds__(256) void k_build_wt(
    const float* __restrict__ Wx, const float* __restrict__ Wh,
    const float* __restrict__ Wattn, unsigned short* __restrict__ WT) {
    __shared__ unsigned short tile[64][72];   // [c_local][k_local], pad 72
    const int k0 = blockIdx.x * 64;           // 48 k-tiles
    const int u0 = blockIdx.y * 16;           // 64 u-tiles
    const int tid = threadIdx.x;
#pragma unroll
    for (int it = 0; it < 16; ++it) {
        int linear = it * 256 + tid;          // 4096 = 64k x 64c
        int kl = linear >> 6;
        int cidx = linear & 63;
        int g = cidx >> 4, uu = cidx & 15;
        int k = k0 + kl;
        int j = g * 1024 + u0 + uu;
        float v;
        if (k < 1024)      v = Wh[k * 4096 + j];
        else if (k < 2048) v = Wattn[(k - 1024) * 4096 + j];
        else               v = Wx[(k - 2048) * 4096 + j];
        tile[4 * uu + g][kl] = f2bf(v);
    }
    __syncthreads();
#pragma unroll
    for (int it = 0; it < 2; ++it) {
        int linear = it * 256 + tid;          // 512 x 8 bf16
        int cl = linear >> 3;
        int seg = (linear & 7) * 8;
        int cg = u0 * 4 + cl;                 // global reordered col
        *(int4*)&WT[(size_t)cg * 3072 + k0 + seg] = *(const int4*)&tile[cl][seg];
    }
}

// ---------------------------------------------------------------------------
// h0 = c0 = mean over the 16 spatial positions of A; also seed act0 h-part.
// ---------------------------------------------------------------------------
__global__ __launch_bounds__(256) void k_init(
    const float* __restrict__ A, float* __restrict__ h, float* __restrict__ c,
    unsigned short* __restrict__ act0) {
    int idx = blockIdx.x * 256 + threadIdx.x;     // 0..131071 = n*1024+u
    const float4* ap = (const float4*)(A + (size_t)idx * 16);
    float4 a0 = ap[0], a1 = ap[1], a2 = ap[2], a3 = ap[3];
    float s = a0.x + a0.y + a0.z + a0.w + a1.x + a1.y + a1.z + a1.w +
              a2.x + a2.y + a2.z + a2.w + a3.x + a3.y + a3.z + a3.w;
    float h0 = s * (1.0f / 16.0f);
    h[idx] = h0;
    c[idx] = h0;
    int n = idx >> 10, u = idx & 1023;
    act0[n * 3072 + u] = f2bf(h0);
}

// ---------------------------------------------------------------------------
// Per-step attention (f32) + pack act = [h | attn | x_t] (bf16).
// One block per n. scores_p = sum_h h[h]*A[n][h][p] * (1/32); softmax;
// attn[u] = sum_p A[n][u][p] * w[p].
// ---------------------------------------------------------------------------
__global__ __launch_bounds__(256) void k_attn(
    const float* __restrict__ A, const float* __restrict__ h,
    const float* __restrict__ x, unsigned short* __restrict__ act, int t) {
    __shared__ float red[16][4];
    __shared__ float wsm[16];
    const int n = blockIdx.x;
    const int tid = threadIdx.x;
    const int lane = tid & 63, wave = tid >> 6;

    const float4 hv = *(const float4*)&h[n * 1024 + tid * 4];
    float hvj[4] = {hv.x, hv.y, hv.z, hv.w};
    float part[16];
#pragma unroll
    for (int p = 0; p < 16; ++p) part[p] = 0.0f;
#pragma unroll
    for (int j = 0; j < 4; ++j) {
        const float4* ar = (const float4*)&A[((size_t)n * 1024 + tid * 4 + j) * 16];
        float4 a0 = ar[0], a1 = ar[1], a2 = ar[2], a3 = ar[3];
        float hh = hvj[j];
        part[0] += hh * a0.x;  part[1] += hh * a0.y;  part[2] += hh * a0.z;  part[3] += hh * a0.w;
        part[4] += hh * a1.x;  part[5] += hh * a1.y;  part[6] += hh * a1.z;  part[7] += hh * a1.w;
        part[8] += hh * a2.x;  part[9] += hh * a2.y;  part[10] += hh * a2.z; part[11] += hh * a2.w;
        part[12] += hh * a3.x; part[13] += hh * a3.y; part[14] += hh * a3.z; part[15] += hh * a3.w;
    }
#pragma unroll
    for (int off = 32; off >= 1; off >>= 1) {
#pragma unroll
        for (int p = 0; p < 16; ++p) part[p] += __shfl_down(part[p], off);
    }
    if (lane == 0) {
#pragma unroll
        for (int p = 0; p < 16; ++p) red[p][wave] = part[p];
    }
    __syncthreads();
    if (tid == 0) {
        float sc[16], mx = -1e30f;
#pragma unroll
        for (int p = 0; p < 16; ++p) {
            sc[p] = (red[p][0] + red[p][1] + red[p][2] + red[p][3]) * 0.03125f;
            mx = fmaxf(mx, sc[p]);
        }
        float se = 0.0f;
#pragma unroll
        for (int p = 0; p < 16; ++p) { sc[p] = expf(sc[p] - mx); se += sc[p]; }
        float inv = 1.0f / se;
#pragma unroll
        for (int p = 0; p < 16; ++p) wsm[p] = sc[p] * inv;
    }
    __syncthreads();
    float w[16];
#pragma unroll
    for (int p = 0; p < 16; ++p) w[p] = wsm[p];

    unsigned short pk[4];
#pragma unroll
    for (int j = 0; j < 4; ++j) {
        const float4* ar = (const float4*)&A[((size_t)n * 1024 + tid * 4 + j) * 16];
        float4 a0 = ar[0], a1 = ar[1], a2 = ar[2], a3 = ar[3];
        float av = w[0] * a0.x + w[1] * a0.y + w[2] * a0.z + w[3] * a0.w +
                   w[4] * a1.x + w[5] * a1.y + w[6] * a1.z + w[7] * a1.w +
                   w[8] * a2.x + w[9] * a2.y + w[10] * a2.z + w[11] * a2.w +
                   w[12] * a3.x + w[13] * a3.y + w[14] * a3.z + w[15] * a3.w;
        pk[j] = f2bf(av);
    }
    *(ushort4*)&act[n * 3072 + 1024 + tid * 4] = make_ushort4(pk[0], pk[1], pk[2], pk[3]);

    const float4 xv = *(const float4*)&x[((size_t)n * 128 + t) * 1024 + tid * 4];
    *(ushort4*)&act[n * 3072 + 2048 + tid * 4] =
        make_ushort4(f2bf(xv.x), f2bf(xv.y), f2bf(xv.z), f2bf(xv.w));
}

// ---------------------------------------------------------------------------
// Per-step fused GEMM + LSTM cell update.
// Block: 32 reordered cols (8 units x 4 gates) x all 128 rows, K=3072.
// 4 waves, each wave a 32x32 tile (2x2 fragments of 16x16x32 bf16 MFMA).
// Epilogue: 4-lane shfl_xor gathers the 4 gates of a unit; writes c,h f32,
// bf16 h into actout (next step's buffer), and out[n][t][u].
// ---------------------------------------------------------------------------
__global__ __launch_bounds__(256) void k_step(
    const unsigned short* __restrict__ WT, const unsigned short* __restrict__ actin,
    unsigned short* __restrict__ actout, const float* __restrict__ b,
    float* __restrict__ h, float* __restrict__ c, float* __restrict__ out, int t) {
    __shared__ unsigned short As[128][72];   // act tile, pad 72 (144B rows, 16B-aligned)
    __shared__ unsigned short Bs[32][72];    // WT tile
    const int tid = threadIdx.x;
    const int lane = tid & 63, wave = tid >> 6;
    const int c0 = blockIdx.x * 32;

    f32x4 acc[2][2] = {};

    for (int k0 = 0; k0 < 3072; k0 += 64) {
        {
            const int r = tid >> 1, hf = (tid & 1) * 32;
            const int4* src = (const int4*)&actin[r * 3072 + k0 + hf];
            int4 v0 = src[0], v1 = src[1], v2 = src[2], v3 = src[3];
            int4* dst = (int4*)&As[r][hf];
            dst[0] = v0; dst[1] = v1; dst[2] = v2; dst[3] = v3;
            const int cl = tid >> 3, seg = (tid & 7) * 8;
            *(int4*)&Bs[cl][seg] = *(const int4*)&WT[(size_t)(c0 + cl) * 3072 + k0 + seg];
        }
        __syncthreads();
#pragma unroll
        for (int kk = 0; kk < 64; kk += 32) {
            const int krd = kk + ((lane >> 4) << 3);
            bf16x8 a0 = *(const bf16x8*)&As[wave * 32 + (lane & 15)][krd];
            bf16x8 a1 = *(const bf16x8*)&As[wave * 32 + 16 + (lane & 15)][krd];
            bf16x8 b0 = *(const bf16x8*)&Bs[lane & 15][krd];
            bf16x8 b1 = *(const bf16x8*)&Bs[16 + (lane & 15)][krd];
            acc[0][0] = __builtin_amdgcn_mfma_f32_16x16x32_bf16(a0, b0, acc[0][0], 0, 0, 0);
            acc[0][1] = __builtin_amdgcn_mfma_f32_16x16x32_bf16(a0, b1, acc[0][1], 0, 0, 0);
            acc[1][0] = __builtin_amdgcn_mfma_f32_16x16x32_bf16(a1, b0, acc[1][0], 0, 0, 0);
            acc[1][1] = __builtin_amdgcn_mfma_f32_16x16x32_bf16(a1, b1, acc[1][1], 0, 0, 0);
        }
        __syncthreads();
    }

    // Epilogue: gates + state update
#pragma unroll
    for (int cf = 0; cf < 2; ++cf) {
        const int col = c0 + cf * 16 + (lane & 15);   // reordered col = 4*u + g
        const int u = col >> 2, g = col & 3;
        const float bias = b[g * 1024 + u];
#pragma unroll
        for (int rf = 0; rf < 2; ++rf) {
#pragma unroll
            for (int reg = 0; reg < 4; ++reg) {
                const int r = wave * 32 + rf * 16 + ((lane >> 4) << 2) + reg;
                float a = acc[rf][cf][reg] + bias;
                float v1 = __shfl_xor(a, 1);
                float v2 = __shfl_xor(a, 2);
                float v3 = __shfl_xor(a, 3);
                // value of gate X lives on lane l^(g^X): pick v_{g^X}
                auto pick = [&](int m) { return m == 0 ? a : m == 1 ? v1 : m == 2 ? v2 : v3; };
                float ii = sigf(pick(g));
                float ff = sigf(pick(g ^ 1));
                float oo = sigf(pick(g ^ 2));
                float gg = tanhf(pick(g ^ 3));
                const float cold = c[r * 1024 + u];
                const float nc = ff * cold + ii * gg;
                const float nh = oo * tanhf(nc);
                if (g == 0)      c[r * 1024 + u] = nc;
                else if (g == 1) h[r * 1024 + u] = nh;
                else if (g == 2) actout[r * 3072 + u] = f2bf(nh);
                else             out[((size_t)r * 128 + t) * 1024 + u] = nh;
            }
        }
    }
}

extern "C" void kernel_launch(void* const* d_in, const int* in_sizes, int n_in,
                              void* d_out, int out_size, void* d_ws, size_t ws_size,
                              hipStream_t stream) {
    const float* x     = (const float*)d_in[0];   // (128,128,1024)
    const float* A     = (const float*)d_in[1];   // (128,1024,4,4)
    const float* Wx    = (const float*)d_in[2];   // (1024,4096)
    const float* Wh    = (const float*)d_in[3];   // (1024,4096)
    const float* Wattn = (const float*)d_in[4];   // (1024,4096)
    const float* b     = (const float*)d_in[5];   // (4096,)
    float* out = (float*)d_out;                   // (128,128,1024) f32

    char* ws = (char*)d_ws;
    // ws layout (needs ~27.8 MB)
    unsigned short* WT   = (unsigned short*)(ws);                         // 4096x3072 bf16 = 25165824
    unsigned short* act0 = (unsigned short*)(ws + 25165824);              // 128x3072 bf16 = 786432
    unsigned short* act1 = (unsigned short*)(ws + 25165824 + 786432);     // 128x3072 bf16
    float* h = (float*)(ws + 25165824 + 2 * 786432);                      // 128x1024 f32
    float* c = (float*)(ws + 25165824 + 2 * 786432 + 524288);             // 128x1024 f32

    k_build_wt<<<dim3(48, 64), 256, 0, stream>>>(Wx, Wh, Wattn, WT);
    k_init<<<512, 256, 0, stream>>>(A, h, c, act0);
    for (int t = 0; t < 128; ++t) {
        unsigned short* ain  = (t & 1) ? act1 : act0;
        unsigned short* aout = (t & 1) ? act0 : act1;
        k_attn<<<128, 256, 0, stream>>>(A, h, x, ain, t);
        k_step<<<128, 256, 0, stream>>>(WT, ain, aout, b, h, c, out, t);
    }
}